// Round 12
// baseline (1601.065 us; speedup 1.0000x reference)
//
#include <hip/hip_runtime.h>

#define T_STEPS 1024
#define FDIM    2048
#define LAT     128
#define HID     256
#define MB      8             // features per block
#define NTHR    256           // 4 waves, 1 per SIMD -> 512-VGPR budget
#define NBLK    (FDIM / MB)   // 256 blocks = 1/CU

typedef __attribute__((ext_vector_type(8))) short bf16x8;
typedef __attribute__((ext_vector_type(4))) float f32x4;

#define L2E  1.4426950408889634f   // log2(e)
#define C2E  2.8853900817779268f   // 2*log2(e)

__device__ __forceinline__ float exp2_(float x) {
#if __has_builtin(__builtin_amdgcn_exp2f)
    return __builtin_amdgcn_exp2f(x);
#else
    return __expf(0.6931471805599453f * x);
#endif
}
__device__ __forceinline__ float rcp_(float x) { return __builtin_amdgcn_rcpf(x); }

__device__ __forceinline__ unsigned short f2bu(float x) {   // fp32->bf16 RNE bits
    unsigned u = __float_as_uint(x);
    u += 0x7fffu + ((u >> 16) & 1u);
    return (unsigned short)(u >> 16);
}
__device__ __forceinline__ short f2b(float x) { return (short)f2bu(x); }
__device__ __forceinline__ unsigned pk2(float a, float b) { // packed bf16x2 RNE
    return (unsigned)f2bu(a) | ((unsigned)f2bu(b) << 16);
}
// pick owned row-pair from a C-fragment: hf=0 -> (v0,v1), hf=1 -> (v2,v3)
__device__ __forceinline__ float2 pick2(f32x4 v, int hf) {
    float a = hf ? v[2] : v[0];
    float b = hf ? v[3] : v[1];
    return make_float2(a, b);
}

// Activation^T LDS layout (B-operand): element (k, m) at short-offset
//   (k>>3)*64 + m*8 + (k&7)   [m in 0..7]
// B-frag read for lane (col,qd): 16B contiguous at (kb*4+qd)*64 + (col&7)*8;
// cols 8..15 duplicate cols 0..7 (same-address broadcast).
//
// 4 waves x 2x tiles each (vs R10's 8 waves x 1x): B-frag reads per wave are
// FIXED (4+8+4 b128) regardless of tiles owned, so CU LDS traffic halves
// (128 -> 64 b128/step). 512-VGPR budget fits 224 weight regs without the
// AGPR-operand move traffic suspected at the 128-cap.

__global__ __launch_bounds__(NTHR, 1)
void odernn_kernel(const float* __restrict__ times,
                   const float* __restrict__ vals,
                   const float* __restrict__ mask,
                   const float* __restrict__ W1,  const float* __restrict__ b1,
                   const float* __restrict__ W2,  const float* __restrict__ b2,
                   const float* __restrict__ W_ih, const float* __restrict__ b_ih,
                   const float* __restrict__ Whh, const float* __restrict__ b_hh,
                   float* __restrict__ out)
{
    __shared__ float dts_s[T_STEPS];   // 4 KB
    __shared__ short hTpre[16 * 64];   // 2 KB  bf16 h^T (post-GRU)
    __shared__ short hTpost[16 * 64];  // 2 KB  bf16 h^T (post-ODE)
    __shared__ short uT[32 * 64];      // 4 KB  bf16 u^T

    const int tid = threadIdx.x;
    const int w   = tid >> 6;          // wave 0..3
    const int ln  = tid & 63;
    const int col = ln & 15;           // C/D col = feature (8..15 duplicate 0..7)
    const int qd  = ln >> 4;           // quad; C/D row = qd*4 + reg
    const int m8  = ln & 7;            // feature index
    const int hf  = (ln >> 3) & 1;     // row-half ownership
    const int fbase = blockIdx.x * MB;
    const int rbase = qd * 64 + m8 * 8;     // B-frag read offset (shorts)

    // ---------- prologue ----------
    for (int e = tid; e < T_STEPS; e += NTHR)
        dts_s[e] = (e == 0) ? 0.0f : (times[T_STEPS - e] - times[T_STEPS - 1 - e]);
    for (int e = tid; e < 16 * 64; e += NTHR) { hTpre[e] = 0; hTpost[e] = 0; }

    // A-operand weight fragment: lane holds W[tb+col][kb*32 + qd*8 + j]
    auto loadW = [&](const float* __restrict__ W, int K, int tb, int kb) -> bf16x8 {
        const float* p = W + (size_t)(tb + col) * K + kb * 32 + qd * 8;
        const float4 a = *(const float4*)p;
        const float4 b = *(const float4*)(p + 4);
        bf16x8 r;
        r[0] = f2b(a.x); r[1] = f2b(a.y); r[2] = f2b(a.z); r[3] = f2b(a.w);
        r[4] = f2b(b.x); r[5] = f2b(b.y); r[6] = f2b(b.z); r[7] = f2b(b.w);
        return r;
    };

    // per-wave tiles (224 weight regs/lane):
    // p1: u-tiles {4w..4w+3}; p2: ode-tiles {2w,2w+1}; p3: gates x tiles {2w,2w+1}
    bf16x8 w1a[4][4];
    #pragma unroll
    for (int i = 0; i < 4; ++i)
        #pragma unroll
        for (int kb = 0; kb < 4; ++kb) w1a[i][kb] = loadW(W1, LAT, (4 * w + i) * 16, kb);
    bf16x8 w2a[2][8];
    #pragma unroll
    for (int i = 0; i < 2; ++i)
        #pragma unroll
        for (int kb = 0; kb < 8; ++kb) w2a[i][kb] = loadW(W2, HID, (2 * w + i) * 16, kb);
    bf16x8 wha[3][2][4];
    #pragma unroll
    for (int g = 0; g < 3; ++g)
        #pragma unroll
        for (int i = 0; i < 2; ++i)
            #pragma unroll
            for (int kb = 0; kb < 4; ++kb)
                wha[g][i][kb] = loadW(Whh, LAT, g * 128 + (2 * w + i) * 16, kb);

    // per-lane constants, pre-scaled into exp2 domain (see R10)
    float cb1L[4][2], b2L[2][2];
    float wrS[2][2], brS[2][2], wzS[2][2], bzS[2][2], wnC[2][2], bnC[2][2], bhnC[2][2];
    #pragma unroll
    for (int i = 0; i < 4; ++i)
        #pragma unroll
        for (int j = 0; j < 2; ++j)
            cb1L[i][j] = C2E * b1[(4 * w + i) * 16 + qd * 4 + hf * 2 + j];
    #pragma unroll
    for (int i = 0; i < 2; ++i)
        #pragma unroll
        for (int j = 0; j < 2; ++j) {
            const int c = (2 * w + i) * 16 + qd * 4 + hf * 2 + j;
            b2L[i][j]  = b2[c];
            wrS[i][j]  = -L2E * W_ih[c];
            brS[i][j]  = -L2E * (b_ih[c] + b_hh[c]);
            wzS[i][j]  = -L2E * W_ih[128 + c];
            bzS[i][j]  = -L2E * (b_ih[128 + c] + b_hh[128 + c]);
            wnC[i][j]  =  C2E * W_ih[256 + c];
            bnC[i][j]  =  C2E * b_ih[256 + c];
            bhnC[i][j] =  C2E * b_hh[256 + c];
        }
    float hreg[2][2] = {{0.f, 0.f}, {0.f, 0.f}};
    int myAddr[2];
    #pragma unroll
    for (int i = 0; i < 2; ++i)
        myAddr[i] = ((2 * w + i) * 2 + (qd >> 1)) * 64 + m8 * 8 + (qd & 1) * 4 + hf * 2;

    const float* vp = vals + (size_t)(T_STEPS - 1) * FDIM + fbase + m8;
    const float* mp = mask + (size_t)(T_STEPS - 1) * FDIM + fbase + m8;

    __syncthreads();

    for (int t = 0; t < T_STEPS; ++t) {
        const float dt = dts_s[t];
        const float x  = *vp;  vp -= FDIM;
        const float mk = *mp;  mp -= FDIM;

        // ---- p1: u^T = tanh(W1 h^T + b1), 4 tiles ----
        f32x4 a1[4] = {{0,0,0,0},{0,0,0,0},{0,0,0,0},{0,0,0,0}};
        #pragma unroll
        for (int kb = 0; kb < 4; ++kb) {
            const bf16x8 bf = *(const bf16x8*)(hTpre + kb * 256 + rbase);
            #pragma unroll
            for (int i = 0; i < 4; ++i)
                a1[i] = __builtin_amdgcn_mfma_f32_16x16x32_bf16(w1a[i][kb], bf, a1[i], 0, 0, 0);
        }
        #pragma unroll
        for (int i = 0; i < 4; ++i) {
            const float2 p = pick2(a1[i], hf);
            const float v0 = fmaf(-2.f, rcp_(1.f + exp2_(fmaf(p.x, C2E, cb1L[i][0]))), 1.f);
            const float v1 = fmaf(-2.f, rcp_(1.f + exp2_(fmaf(p.y, C2E, cb1L[i][1]))), 1.f);
            const int addr = ((4 * w + i) * 2 + (qd >> 1)) * 64 + m8 * 8 + (qd & 1) * 4 + hf * 2;
            *(unsigned*)(uT + addr) = pk2(v0, v1);
        }
        __syncthreads();

        // ---- p2: ode^T = W2 u^T + b2 ; h += dt*ode. 2 tiles, dual-chain each ----
        f32x4 a2a[2] = {{0,0,0,0},{0,0,0,0}}, a2b[2] = {{0,0,0,0},{0,0,0,0}};
        #pragma unroll
        for (int kb = 0; kb < 4; ++kb) {
            const bf16x8 bfa = *(const bf16x8*)(uT + kb * 256 + rbase);
            const bf16x8 bfb = *(const bf16x8*)(uT + (kb + 4) * 256 + rbase);
            #pragma unroll
            for (int i = 0; i < 2; ++i) {
                a2a[i] = __builtin_amdgcn_mfma_f32_16x16x32_bf16(w2a[i][kb],     bfa, a2a[i], 0, 0, 0);
                a2b[i] = __builtin_amdgcn_mfma_f32_16x16x32_bf16(w2a[i][kb + 4], bfb, a2b[i], 0, 0, 0);
            }
        }
        #pragma unroll
        for (int i = 0; i < 2; ++i) {
            const f32x4 a2 = a2a[i] + a2b[i];
            const float2 p = pick2(a2, hf);
            hreg[i][0] = fmaf(dt, p.x + b2L[i][0], hreg[i][0]);
            hreg[i][1] = fmaf(dt, p.y + b2L[i][1], hreg[i][1]);
            *(unsigned*)(hTpost + myAddr[i]) = pk2(hreg[i][0], hreg[i][1]);
        }
        __syncthreads();

        // ---- p3: gh^T = Whh h'^T (+ biases folded), GRU fully in-register ----
        f32x4 a3[3][2] = {{{0,0,0,0},{0,0,0,0}},{{0,0,0,0},{0,0,0,0}},{{0,0,0,0},{0,0,0,0}}};
        #pragma unroll
        for (int kb = 0; kb < 4; ++kb) {
            const bf16x8 bf = *(const bf16x8*)(hTpost + kb * 256 + rbase);
            #pragma unroll
            for (int g = 0; g < 3; ++g)
                #pragma unroll
                for (int i = 0; i < 2; ++i)
                    a3[g][i] = __builtin_amdgcn_mfma_f32_16x16x32_bf16(wha[g][i][kb], bf, a3[g][i], 0, 0, 0);
        }
        #pragma unroll
        for (int i = 0; i < 2; ++i) {
            const float2 gR = pick2(a3[0][i], hf);
            const float2 gZ = pick2(a3[1][i], hf);
            const float2 gN = pick2(a3[2][i], hf);
            const float gRv[2] = {gR.x, gR.y}, gZv[2] = {gZ.x, gZ.y}, gNv[2] = {gN.x, gN.y};
            #pragma unroll
            for (int j = 0; j < 2; ++j) {
                const float sr = rcp_(1.f + exp2_(fmaf(gRv[j], -L2E, fmaf(x, wrS[i][j], brS[i][j]))));
                const float sz = rcp_(1.f + exp2_(fmaf(gZv[j], -L2E, fmaf(x, wzS[i][j], bzS[i][j]))));
                const float yn = fmaf(sr, fmaf(gNv[j], C2E, bhnC[i][j]), fmaf(x, wnC[i][j], bnC[i][j]));
                const float nn = fmaf(-2.f, rcp_(1.f + exp2_(yn)), 1.f);
                const float hv = hreg[i][j];
                const float hc = fmaf(sz, hv - nn, nn);          // (1-z)n + z*h
                hreg[i][j] = fmaf(mk, hc - hv, hv);              // mask blend
            }
            *(unsigned*)(hTpre + myAddr[i]) = pk2(hreg[i][0], hreg[i][1]);
        }
        __syncthreads();
    }

    #pragma unroll
    for (int i = 0; i < 2; ++i) {
        float2 o = make_float2(hreg[i][0], hreg[i][1]);
        *(float2*)(out + (size_t)(fbase + m8) * LAT + (2 * w + i) * 16 + qd * 4 + hf * 2) = o;
    }
}

extern "C" void kernel_launch(void* const* d_in, const int* in_sizes, int n_in,
                              void* d_out, int out_size, void* d_ws, size_t ws_size,
                              hipStream_t stream) {
    const float* times = (const float*)d_in[0];
    const float* vals  = (const float*)d_in[1];
    const float* mask  = (const float*)d_in[2];
    const float* W1    = (const float*)d_in[3];
    const float* b1    = (const float*)d_in[4];
    const float* W2    = (const float*)d_in[5];
    const float* b2    = (const float*)d_in[6];
    const float* W_ih  = (const float*)d_in[7];
    const float* b_ih  = (const float*)d_in[8];
    const float* Whh   = (const float*)d_in[9];
    const float* b_hh  = (const float*)d_in[10];
    float* out = (float*)d_out;

    odernn_kernel<<<NBLK, NTHR, 0, stream>>>(times, vals, mask,
                                             W1, b1, W2, b2,
                                             W_ih, b_ih, Whh, b_hh, out);
}

// Round 13
// 1444.012 us; speedup vs baseline: 1.1088x; 1.1088x over previous
//
#include <hip/hip_runtime.h>

#define T_STEPS 1024
#define FDIM    2048
#define LAT     128
#define HID     256
#define MB      8             // features per block
#define NTHR    512           // 8 waves, 2/SIMD (R12 proved 1/SIMD loses latency hiding)
#define NBLK    (FDIM / MB)   // 256 blocks = 1/CU

typedef __attribute__((ext_vector_type(8))) short bf16x8;
typedef __attribute__((ext_vector_type(4))) float f32x4;

#define L2E  1.4426950408889634f   // log2(e)
#define C2E  2.8853900817779268f   // 2*log2(e)

#if defined(__has_builtin)
# if __has_builtin(__builtin_amdgcn_cvt_pk_fp8_f32)
#  define HAS_CVT_FP8 1
# endif
#endif

__device__ __forceinline__ float exp2_(float x) {
#if __has_builtin(__builtin_amdgcn_exp2f)
    return __builtin_amdgcn_exp2f(x);
#else
    return __expf(0.6931471805599453f * x);
#endif
}
__device__ __forceinline__ float rcp_(float x) { return __builtin_amdgcn_rcpf(x); }

__device__ __forceinline__ unsigned short f2bu(float x) {   // fp32->bf16 RNE bits
    unsigned u = __float_as_uint(x);
    u += 0x7fffu + ((u >> 16) & 1u);
    return (unsigned short)(u >> 16);
}
__device__ __forceinline__ short f2b(float x) { return (short)f2bu(x); }
__device__ __forceinline__ unsigned pk2(float a, float b) { // packed bf16x2 RNE
    return (unsigned)f2bu(a) | ((unsigned)f2bu(b) << 16);
}
__device__ __forceinline__ float2 pick2(f32x4 v, int hf) {  // owned row-pair
    float a = hf ? v[2] : v[0];
    float b = hf ? v[3] : v[1];
    return make_float2(a, b);
}

// fp32 -> OCP e4m3fn, RNE, with subnormals. (prep kernel + hot-path fallback)
__device__ __forceinline__ unsigned char enc_e4m3(float v) {
    float av = fminf(fabsf(v), 448.0f);
    const unsigned s = (__float_as_uint(v) >> 24) & 0x80u;
    const unsigned ub = __float_as_uint(av);
    const unsigned r  = ub + 0x7FFFFu + ((ub >> 20) & 1u);   // RNE to 3 mant bits
    const unsigned en = (r >> 20) - 960u;                    // ((127-7)<<3)
    const unsigned m  = (unsigned)__float2int_rn(av * 512.0f);  // subnormal: m*2^-9
    const unsigned code = (av >= 0.015625f) ? en : m;
    return (unsigned char)(s | code);
}

// ---------- prep: Wc16 = 16*(Whh @ W2) as e4m3, cb = Whh @ b2 (fp32) ----------
// Whh (384,128) row-major; W2 (128,256) row-major (ode_l = sum_c W2[l][c]*u[c]).
__global__ void prep_wc(const float* __restrict__ Whh, const float* __restrict__ W2,
                        const float* __restrict__ b2,
                        unsigned char* __restrict__ wc8, float* __restrict__ cb)
{
    const int r = blockIdx.x;            // 0..383
    const int c = threadIdx.x;           // 0..255
    float acc = 0.0f;
    for (int l = 0; l < LAT; ++l)
        acc = fmaf(Whh[r * LAT + l], W2[l * HID + c], acc);
    wc8[r * HID + c] = enc_e4m3(16.0f * acc);
    if (c == 0) {
        float a = 0.0f;
        for (int l = 0; l < LAT; ++l) a = fmaf(Whh[r * LAT + l], b2[l], a);
        cb[r] = a;
    }
}

// Activation^T LDS layout (B-operand), bf16: element (k,m) at short-offset
//   (k>>3)*64 + m*8 + (k&7); fp8: same but byte-offset. B-frag reads are
// contiguous per lane; cols 8..15 duplicate cols 0..7 (broadcast).

__global__ __launch_bounds__(NTHR, 2)
void odernn_kernel(const float* __restrict__ times,
                   const float* __restrict__ vals,
                   const float* __restrict__ mask,
                   const float* __restrict__ W1,  const float* __restrict__ b1,
                   const float* __restrict__ W2,  const float* __restrict__ b2,
                   const float* __restrict__ W_ih, const float* __restrict__ b_ih,
                   const float* __restrict__ Whh, const float* __restrict__ b_hh,
                   const unsigned char* __restrict__ wc8, const float* __restrict__ cb,
                   float* __restrict__ out)
{
    __shared__ float dts_s[T_STEPS];        // 4 KB
    __shared__ short hTpre[16 * 64];        // 2 KB  bf16 h^T (post-GRU)
    __shared__ short uT[32 * 64];           // 4 KB  bf16 u^T
    __shared__ unsigned char uT8[32 * 64];  // 2 KB  fp8  u^T

    const int tid = threadIdx.x;
    const int w   = tid >> 6;          // wave 0..7
    const int ln  = tid & 63;
    const int col = ln & 15;
    const int qd  = ln >> 4;
    const int m8  = ln & 7;
    const int hf  = (ln >> 3) & 1;
    const int fbase = blockIdx.x * MB;
    const int rbase = qd * 64 + m8 * 8;

    for (int e = tid; e < T_STEPS; e += NTHR)
        dts_s[e] = (e == 0) ? 0.0f : (times[T_STEPS - e] - times[T_STEPS - 1 - e]);
    for (int e = tid; e < 16 * 64; e += NTHR) hTpre[e] = 0;

    auto loadW = [&](const float* __restrict__ W, int K, int tb, int kb) -> bf16x8 {
        const float* p = W + (size_t)(tb + col) * K + kb * 32 + qd * 8;
        const float4 a = *(const float4*)p;
        const float4 b = *(const float4*)(p + 4);
        bf16x8 r;
        r[0] = f2b(a.x); r[1] = f2b(a.y); r[2] = f2b(a.z); r[3] = f2b(a.w);
        r[4] = f2b(b.x); r[5] = f2b(b.y); r[6] = f2b(b.z); r[7] = f2b(b.w);
        return r;
    };

    // Phase-A weights: u-tiles {2w,2w+1} (W1) + gh0 gate-tiles {w,8+w,16+w} (Whh)
    bf16x8 w1a[2][4];
    #pragma unroll
    for (int i = 0; i < 2; ++i)
        #pragma unroll
        for (int kb = 0; kb < 4; ++kb) w1a[i][kb] = loadW(W1, LAT, (2 * w + i) * 16, kb);
    bf16x8 wha[3][4];
    #pragma unroll
    for (int g = 0; g < 3; ++g)
        #pragma unroll
        for (int kb = 0; kb < 4; ++kb)
            wha[g][kb] = loadW(Whh, LAT, g * 128 + w * 16, kb);
    // Phase-B weights: W2 tile {w} bf16 + Wc gate-tiles fp8 (A-frag = 8 bytes = long)
    bf16x8 w2a[8];
    #pragma unroll
    for (int kb = 0; kb < 8; ++kb) w2a[kb] = loadW(W2, HID, w * 16, kb);
    long wca[3][8];
    #pragma unroll
    for (int g = 0; g < 3; ++g)
        #pragma unroll
        for (int kb = 0; kb < 8; ++kb)
            wca[g][kb] = *(const long*)(wc8 + (size_t)(g * 128 + w * 16 + col) * HID + kb * 32 + qd * 8);

    // per-lane constants (owned rows c = w*16 + qd*4 + hf*2 + j), exp2-domain
    float cb1L[2][2], b2L[2], cbL[3][2];
    float wrS[2], brS[2], wzS[2], bzS[2], wnC[2], bnC[2], bhnC[2];
    #pragma unroll
    for (int i = 0; i < 2; ++i)
        #pragma unroll
        for (int j = 0; j < 2; ++j)
            cb1L[i][j] = C2E * b1[(2 * w + i) * 16 + qd * 4 + hf * 2 + j];
    #pragma unroll
    for (int j = 0; j < 2; ++j) {
        const int c = w * 16 + qd * 4 + hf * 2 + j;
        b2L[j]  = b2[c];
        wrS[j]  = -L2E * W_ih[c];
        brS[j]  = -L2E * (b_ih[c] + b_hh[c]);
        wzS[j]  = -L2E * W_ih[128 + c];
        bzS[j]  = -L2E * (b_ih[128 + c] + b_hh[128 + c]);
        wnC[j]  =  C2E * W_ih[256 + c];
        bnC[j]  =  C2E * b_ih[256 + c];
        bhnC[j] =  C2E * b_hh[256 + c];
        #pragma unroll
        for (int g = 0; g < 3; ++g) cbL[g][j] = cb[g * 128 + c];
    }
    float hreg[2] = {0.f, 0.f};
    const int grpBase = (w * 2 + (qd >> 1)) * 64 + m8 * 8 + (qd & 1) * 4 + hf * 2;
    const int myAddr = grpBase;     // hTpre store (shorts)

    const float* vp = vals + (size_t)(T_STEPS - 1) * FDIM + fbase + m8;
    const float* mp = mask + (size_t)(T_STEPS - 1) * FDIM + fbase + m8;

    __syncthreads();

    for (int t = 0; t < T_STEPS; ++t) {
        const float dt = dts_s[t];
        const float x  = *vp;  vp -= FDIM;
        const float mk = *mp;  mp -= FDIM;
        // wave-uniform per-step scalars
        const float mdt    = dt * (-L2E);
        const float mdt16  = mdt * 0.0625f;
        const float cdt    = dt * C2E;
        const float cdt16  = cdt * 0.0625f;

        // ---- Phase A: u = tanh(W1 h + b1) AND gh0 = Whh h (same B-frags) ----
        f32x4 a1[2] = {{0,0,0,0},{0,0,0,0}};
        f32x4 g0[3] = {{0,0,0,0},{0,0,0,0},{0,0,0,0}};
        #pragma unroll
        for (int kb = 0; kb < 4; ++kb) {
            const bf16x8 bf = *(const bf16x8*)(hTpre + kb * 256 + rbase);
            a1[0] = __builtin_amdgcn_mfma_f32_16x16x32_bf16(w1a[0][kb], bf, a1[0], 0, 0, 0);
            a1[1] = __builtin_amdgcn_mfma_f32_16x16x32_bf16(w1a[1][kb], bf, a1[1], 0, 0, 0);
            #pragma unroll
            for (int g = 0; g < 3; ++g)
                g0[g] = __builtin_amdgcn_mfma_f32_16x16x32_bf16(wha[g][kb], bf, g0[g], 0, 0, 0);
        }
        #pragma unroll
        for (int i = 0; i < 2; ++i) {
            const float2 p = pick2(a1[i], hf);
            const float v0 = fmaf(-2.f, rcp_(1.f + exp2_(fmaf(p.x, C2E, cb1L[i][0]))), 1.f);
            const float v1 = fmaf(-2.f, rcp_(1.f + exp2_(fmaf(p.y, C2E, cb1L[i][1]))), 1.f);
            const int ga = ((2 * w + i) * 2 + (qd >> 1)) * 64 + m8 * 8 + (qd & 1) * 4 + hf * 2;
            *(unsigned*)(uT + ga) = pk2(v0, v1);
#ifdef HAS_CVT_FP8
            const int p8 = __builtin_amdgcn_cvt_pk_fp8_f32(v0, v1, 0, false);
            *(unsigned short*)(uT8 + ga) = (unsigned short)(p8 & 0xffff);
#else
            *(unsigned short*)(uT8 + ga) =
                (unsigned short)(enc_e4m3(v0) | ((unsigned)enc_e4m3(v1) << 8));
#endif
        }
        __syncthreads();

        // ---- Phase B: w2u = W2 u (bf16, dual chain); wc = Wc16 u (fp8);
        //      then ODE + GRU fully in registers; write hTpre. ----
        f32x4 a2a = {0,0,0,0}, a2b = {0,0,0,0};
        f32x4 wc[3] = {{0,0,0,0},{0,0,0,0},{0,0,0,0}};
        #pragma unroll
        for (int kb = 0; kb < 4; ++kb) {
            const bf16x8 bfa = *(const bf16x8*)(uT + kb * 256 + rbase);
            const bf16x8 bfb = *(const bf16x8*)(uT + (kb + 4) * 256 + rbase);
            a2a = __builtin_amdgcn_mfma_f32_16x16x32_bf16(w2a[kb],     bfa, a2a, 0, 0, 0);
            a2b = __builtin_amdgcn_mfma_f32_16x16x32_bf16(w2a[kb + 4], bfb, a2b, 0, 0, 0);
        }
        #pragma unroll
        for (int kb = 0; kb < 8; ++kb) {
            const long u8 = *(const long*)(uT8 + (kb * 4 + qd) * 64 + m8 * 8);
            #pragma unroll
            for (int g = 0; g < 3; ++g)
                wc[g] = __builtin_amdgcn_mfma_f32_16x16x32_fp8_fp8(wca[g][kb], u8, wc[g], 0, 0, 0);
        }
        {
            const f32x4 a2 = a2a + a2b;
            const float2 pw = pick2(a2, hf);
            const float hp[2] = { fmaf(dt, pw.x + b2L[0], hreg[0]),
                                  fmaf(dt, pw.y + b2L[1], hreg[1]) };   // h' (post-ODE)
            const float2 r0 = pick2(g0[0], hf), r1 = pick2(wc[0], hf);
            const float2 z0 = pick2(g0[1], hf), z1 = pick2(wc[1], hf);
            const float2 n0 = pick2(g0[2], hf), n1 = pick2(wc[2], hf);
            const float g0r[2] = {r0.x, r0.y}, wcr[2] = {r1.x, r1.y};
            const float g0z[2] = {z0.x, z0.y}, wcz[2] = {z1.x, z1.y};
            const float g0n[2] = {n0.x, n0.y}, wcn[2] = {n1.x, n1.y};
            #pragma unroll
            for (int j = 0; j < 2; ++j) {
                // gh_full = g0 + dt/16*wc + dt*cb (+ b_hh folded in constants)
                const float ar = fmaf(g0r[j], -L2E, fmaf(wcr[j], mdt16,
                                   fmaf(cbL[0][j], mdt, fmaf(x, wrS[j], brS[j]))));
                const float az = fmaf(g0z[j], -L2E, fmaf(wcz[j], mdt16,
                                   fmaf(cbL[1][j], mdt, fmaf(x, wzS[j], bzS[j]))));
                const float sr = rcp_(1.f + exp2_(ar));
                const float sz = rcp_(1.f + exp2_(az));
                const float gn2 = fmaf(g0n[j], C2E, fmaf(wcn[j], cdt16,
                                    fmaf(cbL[2][j], cdt, bhnC[j])));
                const float yn = fmaf(sr, gn2, fmaf(x, wnC[j], bnC[j]));
                const float nn = fmaf(-2.f, rcp_(1.f + exp2_(yn)), 1.f);
                const float hv = hp[j];
                const float hc = fmaf(sz, hv - nn, nn);
                hreg[j] = fmaf(mk, hc - hv, hv);
            }
            *(unsigned*)(hTpre + myAddr) = pk2(hreg[0], hreg[1]);
        }
        __syncthreads();
    }

    {
        float2 o = make_float2(hreg[0], hreg[1]);
        *(float2*)(out + (size_t)(fbase + m8) * LAT + w * 16 + qd * 4 + hf * 2) = o;
    }
}

extern "C" void kernel_launch(void* const* d_in, const int* in_sizes, int n_in,
                              void* d_out, int out_size, void* d_ws, size_t ws_size,
                              hipStream_t stream) {
    const float* times = (const float*)d_in[0];
    const float* vals  = (const float*)d_in[1];
    const float* mask  = (const float*)d_in[2];
    const float* W1    = (const float*)d_in[3];
    const float* b1    = (const float*)d_in[4];
    const float* W2    = (const float*)d_in[5];
    const float* b2    = (const float*)d_in[6];
    const float* W_ih  = (const float*)d_in[7];
    const float* b_ih  = (const float*)d_in[8];
    const float* Whh   = (const float*)d_in[9];
    const float* b_hh  = (const float*)d_in[10];
    float* out = (float*)d_out;

    unsigned char* wc8 = (unsigned char*)d_ws;           // 384*256 = 98304 B
    float*         cbp = (float*)((char*)d_ws + 98304);  // 384 floats

    prep_wc<<<384, 256, 0, stream>>>(Whh, W2, b2, wc8, cbp);
    odernn_kernel<<<NBLK, NTHR, 0, stream>>>(times, vals, mask,
                                             W1, b1, W2, b2,
                                             W_ih, b_ih, Whh, b_hh,
                                             wc8, cbp, out);
}